// Round 8
// baseline (249.554 us; speedup 1.0000x reference)
//
#include <hip/hip_runtime.h>

#define NG 76
#define NPOS (NG * NG)            // 5776
#define NC 85                     // 5 + 80
#define NA 3
#define TP 256                    // positions per wave-tile (4 per lane)
#define TILES 23                  // 22 full + one 144-position tail
#define STRIDE_F 8.0f             // 608 / 76

typedef float f4 __attribute__((ext_vector_type(4)));

// exp(w) * scaled_anchor * stride == exp(w) * ANCHOR  (scaled = ANCHOR/stride)
__constant__ float c_aw[NA] = {10.0f, 16.0f, 33.0f};
__constant__ float c_ah[NA] = {13.0f, 30.0f, 23.0f};

__device__ __forceinline__ float sigm(float x) {
    return __builtin_amdgcn_rcpf(1.0f + __expf(-x));
}
// 16B store at 4B alignment (out rows are 340B): legal via memcpy lowering.
__device__ __forceinline__ void st16(float* p, float a, float b, float c, float d) {
    f4 v = {a, b, c, d};
    __builtin_memcpy(p, &v, 16);
}

// Register-file transpose: one wave owns a 256-pos x 85-ch tile in VGPRs.
//  - loads: lane l reads positions 4l..4l+3 of ONE channel row -> each
//    instruction is a 1KB linear read from one row (copy-identical);
//    32 independent loads in flight per chunk (deep MLP, probes MSHR budget).
//  - stores: per position, 8 back-to-back 16B stores covering a full 128B
//    run -> L2 write-merge window is ~10 instrs (R5's footprint bug fixed).
//  - the 4x4 pos<->ch transpose is free register renaming. No LDS, no barriers.
__global__ __launch_bounds__(256) void det_kernel(const float* __restrict__ in,
                                                  float* __restrict__ out) {
    const int t = threadIdx.x, w = t >> 6, l = t & 63;
    const int sid   = blockIdx.x * 4 + w;           // wave-tile id, 0..1103
    const int plane = sid / TILES;                  // b*NA + a
    const int tile  = sid - plane * TILES;
    const int a     = plane % NA;
    const float aw = c_aw[a], ah = c_ah[a];

    const int pp  = tile * TP + l * 4;              // lane's first position
    const bool act = (pp < NPOS);                   // tail tile: lanes 36+ off
    const int pr  = act ? pp : (NPOS - 4);          // clamped read base

    const float* ip = in + (size_t)plane * (NC * NPOS) + pr;
    float*       op = out + ((size_t)plane * NPOS + pp) * NC;  // used iff act

    // ---------------- chunk 0: channels 0..31 (includes box) ----------------
    {
        f4 b[32];
        #pragma unroll
        for (int j = 0; j < 32; ++j)
            b[j] = *reinterpret_cast<const f4*>(ip + j * NPOS);

        // box: 4-aligned position group never crosses a grid row (76%4==0)
        const int gy  = (int)((unsigned)pr / (unsigned)NG);
        const int gx0 = pr - gy * NG;
        const float gyf = (float)gy, gxf = (float)gx0;
        { f4 v = b[0];                               // ch0: x center
          b[0].x = (sigm(v.x) + gxf)        * STRIDE_F;
          b[0].y = (sigm(v.y) + gxf + 1.0f) * STRIDE_F;
          b[0].z = (sigm(v.z) + gxf + 2.0f) * STRIDE_F;
          b[0].w = (sigm(v.w) + gxf + 3.0f) * STRIDE_F; }
        { f4 v = b[1];                               // ch1: y center
          b[1].x = (sigm(v.x) + gyf) * STRIDE_F;
          b[1].y = (sigm(v.y) + gyf) * STRIDE_F;
          b[1].z = (sigm(v.z) + gyf) * STRIDE_F;
          b[1].w = (sigm(v.w) + gyf) * STRIDE_F; }
        { f4 v = b[2];                               // ch2: w
          b[2].x = __expf(v.x) * aw; b[2].y = __expf(v.y) * aw;
          b[2].z = __expf(v.z) * aw; b[2].w = __expf(v.w) * aw; }
        { f4 v = b[3];                               // ch3: h
          b[3].x = __expf(v.x) * ah; b[3].y = __expf(v.y) * ah;
          b[3].z = __expf(v.z) * ah; b[3].w = __expf(v.w) * ah; }
        #pragma unroll
        for (int j = 4; j < 32; ++j) {               // conf + classes
            f4 v = b[j];
            b[j].x = sigm(v.x); b[j].y = sigm(v.y);
            b[j].z = sigm(v.z); b[j].w = sigm(v.w);
        }
        if (act) {
            #pragma unroll
            for (int k = 0; k < 4; ++k) {            // position pp+k
                float* o = op + k * NC;              // 128B burst, back-to-back
                #pragma unroll
                for (int m = 0; m < 8; ++m)
                    st16(o + m * 4, b[4*m+0][k], b[4*m+1][k],
                                    b[4*m+2][k], b[4*m+3][k]);
            }
        }
    }

    // ---------------- chunk 1: channels 32..63 (pure sigmoid) ----------------
    {
        f4 b[32];
        #pragma unroll
        for (int j = 0; j < 32; ++j)
            b[j] = *reinterpret_cast<const f4*>(ip + (32 + j) * NPOS);
        #pragma unroll
        for (int j = 0; j < 32; ++j) {
            f4 v = b[j];
            b[j].x = sigm(v.x); b[j].y = sigm(v.y);
            b[j].z = sigm(v.z); b[j].w = sigm(v.w);
        }
        if (act) {
            #pragma unroll
            for (int k = 0; k < 4; ++k) {
                float* o = op + k * NC + 32;
                #pragma unroll
                for (int m = 0; m < 8; ++m)
                    st16(o + m * 4, b[4*m+0][k], b[4*m+1][k],
                                    b[4*m+2][k], b[4*m+3][k]);
            }
        }
    }

    // ---------------- chunk 2: channels 64..84 (pure sigmoid) ----------------
    {
        f4 b[21];
        #pragma unroll
        for (int j = 0; j < 21; ++j)
            b[j] = *reinterpret_cast<const f4*>(ip + (64 + j) * NPOS);
        #pragma unroll
        for (int j = 0; j < 21; ++j) {
            f4 v = b[j];
            b[j].x = sigm(v.x); b[j].y = sigm(v.y);
            b[j].z = sigm(v.z); b[j].w = sigm(v.w);
        }
        if (act) {
            #pragma unroll
            for (int k = 0; k < 4; ++k) {
                float* o = op + k * NC + 64;
                #pragma unroll
                for (int m = 0; m < 5; ++m)          // ch 64..83
                    st16(o + m * 4, b[4*m+0][k], b[4*m+1][k],
                                    b[4*m+2][k], b[4*m+3][k]);
                o[20] = b[20][k];                    // ch 84
            }
        }
    }
}

extern "C" void kernel_launch(void* const* d_in, const int* in_sizes, int n_in,
                              void* d_out, int out_size, void* d_ws, size_t ws_size,
                              hipStream_t stream) {
    const float* x = (const float*)d_in[0];
    float* out     = (float*)d_out;
    const int nB     = in_sizes[0] / (NA * NC * NPOS);   // 16
    const int waves  = nB * NA * TILES;                  // 1104 wave-tiles
    const int blocks = waves / 4;                        // 276 blocks x 4 waves
    det_kernel<<<blocks, 256, 0, stream>>>(x, out);
}

// Round 9
// 164.094 us; speedup vs baseline: 1.5208x; 1.5208x over previous
//
#include <hip/hip_runtime.h>

#define NG 76
#define NPOS (NG * NG)            // 5776
#define NC 85                     // 5 + 80
#define NA 3
#define SPOS 16                   // positions per wave-strip
#define SPP (NPOS / SPOS)         // 361 strips per plane (exact)
#define WPB 4                     // waves per block (256 threads)
#define STRIDE_F 8.0f             // 608 / 76

typedef float f4 __attribute__((ext_vector_type(4)));

// exp(w) * scaled_anchor * stride == exp(w) * ANCHOR  (scaled = ANCHOR/stride)
__constant__ float c_aw[NA] = {10.0f, 16.0f, 33.0f};
__constant__ float c_ah[NA] = {13.0f, 30.0f, 23.0f};

__device__ __forceinline__ float sigm(float x) {
    return __builtin_amdgcn_rcpf(1.0f + __expf(-x));
}

// R7 body (wave-private LDS strip, no barriers, transform-on-load) with ONE
// change: all 6 global loads are issued up-front and pinned live in VGPRs by
// an empty asm with "+v" constraints. Rounds 3/4/7/8 (VGPR=32/20/36/72)
// prove the compiler otherwise sinks each load into its use -> 1 load in
// flight per wave -> read stream capped at ~1.6 TB/s by concurrency.
__global__ __launch_bounds__(256) void det_kernel(const float* __restrict__ in,
                                                  float* __restrict__ out) {
    __shared__ __align__(16) float lds[WPB][SPOS * NC];   // 4 x 5440 B

    const int t   = threadIdx.x;
    const int w   = t >> 6;                               // wave in block
    const int l   = t & 63;                               // lane
    const int sid = blockIdx.x * WPB + w;                 // global strip id
    const int plane = (int)((unsigned)sid / (unsigned)SPP);  // b*NA + a
    const int strip = sid - plane * SPP;
    const int a     = plane - (plane / NA) * NA;
    const int pos0  = strip * SPOS;
    const float aw = c_aw[a];
    const float ah = c_ah[a];

    const float* ip = in  + (size_t)plane * (NC * NPOS) + pos0;
    float*       op = out + (size_t)plane * (NPOS * NC) + (size_t)pos0 * NC;
    float* L = lds[w];

    constexpr int NV = NC * 4;                            // 340 f4 per strip

    // ---- phase 1: issue ALL 6 loads back-to-back (deep MLP) ----
    f4 r[6];
    #pragma unroll
    for (int i = 0; i < 6; ++i) {
        int v = l + i * 64;
        v = v < NV ? v : NV - 1;                          // clamp: dups benign
        const int c  = v >> 2;
        const int pq = v & 3;
        r[i] = *reinterpret_cast<const f4*>(ip + c * NPOS + pq * 4);
    }
    // MLP pin: all six results must be resident in VGPRs here -> compiler
    // cannot sink the loads; it still inserts its own counted s_waitcnt.
    asm volatile("" : "+v"(r[0]), "+v"(r[1]), "+v"(r[2]),
                      "+v"(r[3]), "+v"(r[4]), "+v"(r[5]));

    // ---- phase 2, iter 0: channels 0..15 (only divergent iter) ----
    {
        const int c  = l >> 2;                            // 0..15
        const int pq = l & 3;
        const f4 f = r[0];
        f4 o;
        if (c >= 4) {                                     // conf/classes
            o.x = sigm(f.x); o.y = sigm(f.y); o.z = sigm(f.z); o.w = sigm(f.w);
        } else if (c == 2) {                              // box w
            o.x = __expf(f.x) * aw; o.y = __expf(f.y) * aw;
            o.z = __expf(f.z) * aw; o.w = __expf(f.w) * aw;
        } else if (c == 3) {                              // box h
            o.x = __expf(f.x) * ah; o.y = __expf(f.y) * ah;
            o.z = __expf(f.z) * ah; o.w = __expf(f.w) * ah;
        } else {
            // c==0/1: 4-aligned position group never crosses a row (76%4==0)
            const int pbase = pos0 + pq * 4;
            const int gy  = (int)((unsigned)pbase / (unsigned)NG);
            const int gx0 = pbase - gy * NG;
            if (c == 0) {
                const float g0 = (float)gx0;
                o.x = (sigm(f.x) + g0)        * STRIDE_F;
                o.y = (sigm(f.y) + g0 + 1.0f) * STRIDE_F;
                o.z = (sigm(f.z) + g0 + 2.0f) * STRIDE_F;
                o.w = (sigm(f.w) + g0 + 3.0f) * STRIDE_F;
            } else {
                const float gyf = (float)gy;
                o.x = (sigm(f.x) + gyf) * STRIDE_F;
                o.y = (sigm(f.y) + gyf) * STRIDE_F;
                o.z = (sigm(f.z) + gyf) * STRIDE_F;
                o.w = (sigm(f.w) + gyf) * STRIDE_F;
            }
        }
        const int pb = pq * 4;
        L[(pb + 0) * NC + c] = o.x;                       // <=3-way alias: free
        L[(pb + 1) * NC + c] = o.y;
        L[(pb + 2) * NC + c] = o.z;
        L[(pb + 3) * NC + c] = o.w;
    }

    // ---- phase 2, iters 1..5: c >= 16 -> pure sigmoid, no decode ----
    #pragma unroll
    for (int i = 1; i < 6; ++i) {
        int v = l + i * 64;
        v = v < NV ? v : NV - 1;
        const int c  = v >> 2;
        const int pq = v & 3;
        const f4 f = r[i];
        const int pb = pq * 4;
        L[(pb + 0) * NC + c] = sigm(f.x);
        L[(pb + 1) * NC + c] = sigm(f.y);
        L[(pb + 2) * NC + c] = sigm(f.z);
        L[(pb + 3) * NC + c] = sigm(f.w);
    }

    // Wave-synchronous LDS handoff (DS pipe in-order per wave); proven R6/R7.
    asm volatile("s_waitcnt lgkmcnt(0)" ::: "memory");

    // ---- phase 3: pure LDS->global copy, zero VALU ----
    #pragma unroll
    for (int i = 0; i < 6; ++i) {
        int v = l + i * 64;
        v = v < NV ? v : NV - 1;                          // dup store benign
        const f4 o = *reinterpret_cast<const f4*>(&L[v * 4]);
        *reinterpret_cast<f4*>(op + v * 4) = o;
    }
}

extern "C" void kernel_launch(void* const* d_in, const int* in_sizes, int n_in,
                              void* d_out, int out_size, void* d_ws, size_t ws_size,
                              hipStream_t stream) {
    const float* x = (const float*)d_in[0];
    float* out     = (float*)d_out;
    const int nB     = in_sizes[0] / (NA * NC * NPOS);    // 16
    const int blocks = nB * NA * SPP / WPB;               // 17328/4 = 4332
    det_kernel<<<blocks, 256, 0, stream>>>(x, out);
}